// Round 1
// baseline (2840.147 us; speedup 1.0000x reference)
//
#include <hip/hip_runtime.h>
#include <math.h>

#define BB   2
#define NPTS 16384
#define KNB  16
#define DPTS 64
#define DM   128

// ======================= Kernel 1: x = fc1(features); q/k/v =======================
#define K1_MT 32   // points per block

__global__ __launch_bounds__(256) void proj_kernel(
    const float* __restrict__ features,
    const float* __restrict__ fc1_w, const float* __restrict__ fc1_b,
    const float* __restrict__ wq, const float* __restrict__ wk, const float* __restrict__ wv,
    float* __restrict__ qws, float* __restrict__ kws, float* __restrict__ vws)
{
    __shared__ float featL[K1_MT][DPTS];
    __shared__ float xL[K1_MT][DM];
    const int tid = threadIdx.x;
    const size_t gp0 = (size_t)blockIdx.x * K1_MT;   // global point index base (b*N+m)

    // stage features tile (contiguous rows)
    const float* fsrc = features + gp0 * DPTS;
    for (int i = tid; i < K1_MT * DPTS / 4; i += 256)
        ((float4*)featL)[i] = ((const float4*)fsrc)[i];
    __syncthreads();

    const int f  = tid & (DM - 1);
    const int r0 = (tid >> 7) * (K1_MT / 2);

    // x = features @ fc1_w.T + fc1_b  -> LDS
    {
        float acc[K1_MT / 2];
        const float bia = fc1_b[f];
#pragma unroll
        for (int r = 0; r < K1_MT / 2; ++r) acc[r] = bia;
        for (int c = 0; c < DPTS; c += 4) {
            const float4 w4 = *(const float4*)&fc1_w[f * DPTS + c];
#pragma unroll
            for (int r = 0; r < K1_MT / 2; ++r) {
                const float4 a4 = *(const float4*)&featL[r0 + r][c];
                acc[r] = fmaf(a4.x, w4.x, fmaf(a4.y, w4.y, fmaf(a4.z, w4.z, fmaf(a4.w, w4.w, acc[r]))));
            }
        }
#pragma unroll
        for (int r = 0; r < K1_MT / 2; ++r) xL[r0 + r][f] = acc[r];
    }
    __syncthreads();

    // q = x@wq.T ; kx = x@wk.T ; vx = x@wv.T   (no bias)
    float aq[K1_MT / 2], ak[K1_MT / 2], av[K1_MT / 2];
#pragma unroll
    for (int r = 0; r < K1_MT / 2; ++r) { aq[r] = 0.f; ak[r] = 0.f; av[r] = 0.f; }
    for (int c = 0; c < DM; c += 4) {
        const float4 wq4 = *(const float4*)&wq[f * DM + c];
        const float4 wk4 = *(const float4*)&wk[f * DM + c];
        const float4 wv4 = *(const float4*)&wv[f * DM + c];
#pragma unroll
        for (int r = 0; r < K1_MT / 2; ++r) {
            const float4 a4 = *(const float4*)&xL[r0 + r][c];
            aq[r] = fmaf(a4.x, wq4.x, fmaf(a4.y, wq4.y, fmaf(a4.z, wq4.z, fmaf(a4.w, wq4.w, aq[r]))));
            ak[r] = fmaf(a4.x, wk4.x, fmaf(a4.y, wk4.y, fmaf(a4.z, wk4.z, fmaf(a4.w, wk4.w, ak[r]))));
            av[r] = fmaf(a4.x, wv4.x, fmaf(a4.y, wv4.y, fmaf(a4.z, wv4.z, fmaf(a4.w, wv4.w, av[r]))));
        }
    }
#pragma unroll
    for (int r = 0; r < K1_MT / 2; ++r) {
        const size_t o = (gp0 + r0 + r) * DM + f;
        qws[o] = aq[r]; kws[o] = ak[r]; vws[o] = av[r];
    }
}

// ======================= Kernel 2: fused neighbor pipeline =======================
#define K2_PTS 4                   // points per block
#define K2_R   (K2_PTS * KNB)      // 64 neighbor-rows
#define ASTR   132                 // padded LDS row stride (floats); 132*4=528B, 16B-aligned

__device__ __forceinline__ void gemm_tile(const float* __restrict__ src,
                                          const float* __restrict__ W,
                                          float acc[4][8], int r0, int f0)
{
    for (int c = 0; c < DM; c += 4) {
        float4 a4[4];
#pragma unroll
        for (int rr = 0; rr < 4; ++rr)
            a4[rr] = *(const float4*)&src[(r0 + rr) * ASTR + c];
#pragma unroll
        for (int ff = 0; ff < 8; ++ff) {
            const float4 w4 = *(const float4*)&W[(f0 + ff) * DM + c];
#pragma unroll
            for (int rr = 0; rr < 4; ++rr) {
                acc[rr][ff] = fmaf(a4[rr].x, w4.x, fmaf(a4[rr].y, w4.y,
                               fmaf(a4[rr].z, w4.z, fmaf(a4[rr].w, w4.w, acc[rr][ff]))));
            }
        }
    }
}

__global__ __launch_bounds__(256) void attn_kernel(
    const float* __restrict__ new_xyz, const float* __restrict__ grouped_xyz,
    const int* __restrict__ grouped_idx,
    const float* __restrict__ dw1, const float* __restrict__ db1,
    const float* __restrict__ dw2, const float* __restrict__ db2,
    const float* __restrict__ gw1, const float* __restrict__ gb1,
    const float* __restrict__ gw2, const float* __restrict__ gb2,
    const float* __restrict__ qws, const float* __restrict__ kws, const float* __restrict__ vws,
    float* __restrict__ out)
{
    __shared__ float ACT[K2_R * ASTR];
    __shared__ float POS[K2_R * ASTR];
    __shared__ float QB[K2_PTS * DM];
    __shared__ float REL[K2_R * 4];
    __shared__ int   IDX[K2_R];

    const int tid = threadIdx.x;
    const int b   = blockIdx.x / (NPTS / K2_PTS);
    const int m0  = (blockIdx.x % (NPTS / K2_PTS)) * K2_PTS;
    const size_t gp0 = (size_t)b * NPTS + m0;
    const float inv_sqrt_d = 0.08838834764831845f;  // 1/sqrt(128)

    // stage q tile
    for (int i = tid; i < K2_PTS * DM; i += 256) QB[i] = qws[gp0 * DM + i];
    // per-row idx + rel
    if (tid < K2_R) {
        const int p = tid / KNB, j = tid % KNB;
        const size_t m = gp0 + p;           // b*N + (m0+p)
        const int mi = m0 + p;
        IDX[tid] = grouped_idx[m * KNB + j];
#pragma unroll
        for (int c = 0; c < 3; ++c)
            REL[tid * 4 + c] = new_xyz[m * 3 + c]
                             - grouped_xyz[(((size_t)b * 3 + c) * NPTS + mi) * KNB + j];
    }
    __syncthreads();

    // inner1 = relu(rel @ dw1.T + db1) -> ACT
    for (int i = tid; i < K2_R * DM; i += 256) {
        const int r = i >> 7, f = i & (DM - 1);
        float v = db1[f];
        v = fmaf(REL[r * 4 + 0], dw1[f * 3 + 0], v);
        v = fmaf(REL[r * 4 + 1], dw1[f * 3 + 1], v);
        v = fmaf(REL[r * 4 + 2], dw1[f * 3 + 2], v);
        ACT[r * ASTR + f] = fmaxf(v, 0.f);
    }
    __syncthreads();

    const int r0 = (tid >> 4) * 4;   // 16 row-groups * 4 rows
    const int f0 = (tid & 15) * 8;   // 16 col-groups * 8 cols

    // GEMM1: pos = inner1 @ dw2.T + db2 -> POS
    {
        float acc[4][8];
#pragma unroll
        for (int rr = 0; rr < 4; ++rr)
#pragma unroll
            for (int ff = 0; ff < 8; ++ff) acc[rr][ff] = 0.f;
        gemm_tile(ACT, dw2, acc, r0, f0);
#pragma unroll
        for (int rr = 0; rr < 4; ++rr)
#pragma unroll
            for (int ff = 0; ff < 8; ++ff)
                POS[(r0 + rr) * ASTR + f0 + ff] = acc[rr][ff] + db2[f0 + ff];
    }
    __syncthreads();   // POS ready; all reads of ACT(inner1) done

    // h = q - k_gather + pos -> ACT
    for (int i = tid; i < K2_R * DM; i += 256) {
        const int r = i >> 7, f = i & (DM - 1);
        const int p = r / KNB;
        const float kv = kws[((size_t)b * NPTS + IDX[r]) * DM + f];
        ACT[r * ASTR + f] = QB[p * DM + f] - kv + POS[r * ASTR + f];
    }
    __syncthreads();

    // GEMM2: g1 = relu(h @ gw1.T + gb1) -> ACT
    {
        float acc[4][8];
#pragma unroll
        for (int rr = 0; rr < 4; ++rr)
#pragma unroll
            for (int ff = 0; ff < 8; ++ff) acc[rr][ff] = 0.f;
        gemm_tile(ACT, gw1, acc, r0, f0);
        __syncthreads();   // all reads of ACT(h) done
#pragma unroll
        for (int rr = 0; rr < 4; ++rr)
#pragma unroll
            for (int ff = 0; ff < 8; ++ff)
                ACT[(r0 + rr) * ASTR + f0 + ff] = fmaxf(acc[rr][ff] + gb1[f0 + ff], 0.f);
    }
    __syncthreads();

    // GEMM3: logits = (g1 @ gw2.T + gb2) * inv_sqrt_d -> ACT
    {
        float acc[4][8];
#pragma unroll
        for (int rr = 0; rr < 4; ++rr)
#pragma unroll
            for (int ff = 0; ff < 8; ++ff) acc[rr][ff] = 0.f;
        gemm_tile(ACT, gw2, acc, r0, f0);
        __syncthreads();   // all reads of ACT(g1) done
#pragma unroll
        for (int rr = 0; rr < 4; ++rr)
#pragma unroll
            for (int ff = 0; ff < 8; ++ff)
                ACT[(r0 + rr) * ASTR + f0 + ff] = (acc[rr][ff] + gb2[f0 + ff]) * inv_sqrt_d;
    }
    __syncthreads();

    // softmax over K (neighbor axis) per (p,f); out = sum_j softmax * (v_gather + pos)
    for (int t = 0; t < (K2_PTS * DM) / 256; ++t) {
        const int i = tid + t * 256;
        const int f = i & (DM - 1), p = i >> 7;
        const int rb = p * KNB;
        float mx = -1e30f;
#pragma unroll
        for (int j = 0; j < KNB; ++j)
            mx = fmaxf(mx, ACT[(rb + j) * ASTR + f]);
        float s = 0.f, o = 0.f;
#pragma unroll
        for (int j = 0; j < KNB; ++j) {
            const float e = __expf(ACT[(rb + j) * ASTR + f] - mx);
            s += e;
            const float vv = vws[((size_t)b * NPTS + IDX[rb + j]) * DM + f]
                           + POS[(rb + j) * ASTR + f];
            o = fmaf(e, vv, o);
        }
        out[(gp0 + p) * DM + f] = o / s;
    }
}

// ======================= launch =======================
extern "C" void kernel_launch(void* const* d_in, const int* in_sizes, int n_in,
                              void* d_out, int out_size, void* d_ws, size_t ws_size,
                              hipStream_t stream)
{
    const float* new_xyz     = (const float*)d_in[0];
    const float* grouped_xyz = (const float*)d_in[1];
    const int*   grouped_idx = (const int*)d_in[2];
    const float* features    = (const float*)d_in[3];
    const float* fc1_w = (const float*)d_in[4];
    const float* fc1_b = (const float*)d_in[5];
    const float* wq    = (const float*)d_in[6];
    const float* wk    = (const float*)d_in[7];
    const float* wv    = (const float*)d_in[8];
    const float* dw1   = (const float*)d_in[9];
    const float* db1   = (const float*)d_in[10];
    const float* dw2   = (const float*)d_in[11];
    const float* db2   = (const float*)d_in[12];
    const float* gw1   = (const float*)d_in[13];
    const float* gb1   = (const float*)d_in[14];
    const float* gw2   = (const float*)d_in[15];
    const float* gb2   = (const float*)d_in[16];
    float* out = (float*)d_out;

    float* ws  = (float*)d_ws;
    const size_t npt = (size_t)BB * NPTS * DM;   // 4,194,304 floats per array
    float* qws = ws;
    float* kws = ws + npt;
    float* vws = ws + 2 * npt;

    proj_kernel<<<(BB * NPTS) / K1_MT, 256, 0, stream>>>(
        features, fc1_w, fc1_b, wq, wk, wv, qws, kws, vws);

    attn_kernel<<<(BB * NPTS) / K2_PTS, 256, 0, stream>>>(
        new_xyz, grouped_xyz, grouped_idx,
        dw1, db1, dw2, db2, gw1, gb1, gw2, gb2,
        qws, kws, vws, out);
}

// Round 2
// 389.926 us; speedup vs baseline: 7.2838x; 7.2838x over previous
//
#include <hip/hip_runtime.h>
#include <math.h>

#define BB   2
#define NPTS 16384
#define KNB  16
#define DPTS 64
#define DM   128

typedef float  f32x4  __attribute__((ext_vector_type(4)));
typedef short  bf16x8 __attribute__((ext_vector_type(8)));

__device__ __forceinline__ unsigned short f2bf(float f) {
    union { float f; unsigned u; } v; v.f = f;
    unsigned r = v.u + 0x7FFFu + ((v.u >> 16) & 1u);   // RNE
    return (unsigned short)(r >> 16);
}

// ======================= Kernel 1: x = fc1(features); q/k/v (f32, unchanged) ===
#define K1_MT 32

__global__ __launch_bounds__(256) void proj_kernel(
    const float* __restrict__ features,
    const float* __restrict__ fc1_w, const float* __restrict__ fc1_b,
    const float* __restrict__ wq, const float* __restrict__ wk, const float* __restrict__ wv,
    float* __restrict__ qws, float* __restrict__ kws, float* __restrict__ vws)
{
    __shared__ float featL[K1_MT][DPTS];
    __shared__ float xL[K1_MT][DM];
    const int tid = threadIdx.x;
    const size_t gp0 = (size_t)blockIdx.x * K1_MT;

    const float* fsrc = features + gp0 * DPTS;
    for (int i = tid; i < K1_MT * DPTS / 4; i += 256)
        ((float4*)featL)[i] = ((const float4*)fsrc)[i];
    __syncthreads();

    const int f  = tid & (DM - 1);
    const int r0 = (tid >> 7) * (K1_MT / 2);

    {
        float acc[K1_MT / 2];
        const float bia = fc1_b[f];
#pragma unroll
        for (int r = 0; r < K1_MT / 2; ++r) acc[r] = bia;
        for (int c = 0; c < DPTS; c += 4) {
            const float4 w4 = *(const float4*)&fc1_w[f * DPTS + c];
#pragma unroll
            for (int r = 0; r < K1_MT / 2; ++r) {
                const float4 a4 = *(const float4*)&featL[r0 + r][c];
                acc[r] = fmaf(a4.x, w4.x, fmaf(a4.y, w4.y, fmaf(a4.z, w4.z, fmaf(a4.w, w4.w, acc[r]))));
            }
        }
#pragma unroll
        for (int r = 0; r < K1_MT / 2; ++r) xL[r0 + r][f] = acc[r];
    }
    __syncthreads();

    float aq[K1_MT / 2], ak[K1_MT / 2], av[K1_MT / 2];
#pragma unroll
    for (int r = 0; r < K1_MT / 2; ++r) { aq[r] = 0.f; ak[r] = 0.f; av[r] = 0.f; }
    for (int c = 0; c < DM; c += 4) {
        const float4 wq4 = *(const float4*)&wq[f * DM + c];
        const float4 wk4 = *(const float4*)&wk[f * DM + c];
        const float4 wv4 = *(const float4*)&wv[f * DM + c];
#pragma unroll
        for (int r = 0; r < K1_MT / 2; ++r) {
            const float4 a4 = *(const float4*)&xL[r0 + r][c];
            aq[r] = fmaf(a4.x, wq4.x, fmaf(a4.y, wq4.y, fmaf(a4.z, wq4.z, fmaf(a4.w, wq4.w, aq[r]))));
            ak[r] = fmaf(a4.x, wk4.x, fmaf(a4.y, wk4.y, fmaf(a4.z, wk4.z, fmaf(a4.w, wk4.w, ak[r]))));
            av[r] = fmaf(a4.x, wv4.x, fmaf(a4.y, wv4.y, fmaf(a4.z, wv4.z, fmaf(a4.w, wv4.w, av[r]))));
        }
    }
#pragma unroll
    for (int r = 0; r < K1_MT / 2; ++r) {
        const size_t o = (gp0 + r0 + r) * DM + f;
        qws[o] = aq[r]; kws[o] = ak[r]; vws[o] = av[r];
    }
}

// ======================= Kernel 2: fused neighbor pipeline (MFMA bf16) =========
#define K2_PTS 4
#define K2_R   (K2_PTS * KNB)   // 64 rows
#define ABSTR  136              // bf16 elems per LDS activation row (272B)
#define PSTR   129              // f32 elems per POS row

__device__ __forceinline__ bf16x8 load_bfrag(const float* __restrict__ W, int n, int k0) {
    const float4 w0 = *(const float4*)&W[n * DM + k0];
    const float4 w1 = *(const float4*)&W[n * DM + k0 + 4];
    bf16x8 r;
    r[0] = (short)f2bf(w0.x); r[1] = (short)f2bf(w0.y);
    r[2] = (short)f2bf(w0.z); r[3] = (short)f2bf(w0.w);
    r[4] = (short)f2bf(w1.x); r[5] = (short)f2bf(w1.y);
    r[6] = (short)f2bf(w1.z); r[7] = (short)f2bf(w1.w);
    return r;
}

// GEMM over the 64x128 activation tile: acc[rt][ct] += AB @ W^T (strip of 32 cols/wave)
__device__ __forceinline__ void mfma_gemm(const unsigned short* __restrict__ AB,
                                          const float* __restrict__ W,
                                          int lane, int wbase, f32x4 acc[4][2])
{
    const int c = lane & 15, g = lane >> 4;
    bf16x8 Bf[2][4];
#pragma unroll
    for (int ct = 0; ct < 2; ++ct)
#pragma unroll
        for (int ks = 0; ks < 4; ++ks)
            Bf[ct][ks] = load_bfrag(W, wbase + ct * 16 + c, ks * 32 + g * 8);
#pragma unroll
    for (int rt = 0; rt < 4; ++rt) {
        bf16x8 Af[4];
#pragma unroll
        for (int ks = 0; ks < 4; ++ks)
            Af[ks] = *(const bf16x8*)&AB[(rt * 16 + c) * ABSTR + ks * 32 + g * 8];
#pragma unroll
        for (int ct = 0; ct < 2; ++ct)
#pragma unroll
            for (int ks = 0; ks < 4; ++ks)
                acc[rt][ct] = __builtin_amdgcn_mfma_f32_16x16x32_bf16(
                    Af[ks], Bf[ct][ks], acc[rt][ct], 0, 0, 0);
    }
}

__global__ __launch_bounds__(256) void attn_kernel(
    const float* __restrict__ new_xyz, const float* __restrict__ grouped_xyz,
    const int* __restrict__ grouped_idx,
    const float* __restrict__ dw1, const float* __restrict__ db1,
    const float* __restrict__ dw2, const float* __restrict__ db2,
    const float* __restrict__ gw1, const float* __restrict__ gb1,
    const float* __restrict__ gw2, const float* __restrict__ gb2,
    const float* __restrict__ qws, const float* __restrict__ kws, const float* __restrict__ vws,
    float* __restrict__ out)
{
    __shared__ __align__(16) unsigned short AB[K2_R * ABSTR];  // 17408 B
    __shared__ __align__(16) float POSL[K2_R * PSTR];          // 33024 B
    __shared__ float REL[K2_R * 3];
    __shared__ int   IDX[K2_R];

    const int tid  = threadIdx.x;
    const int lane = tid & 63;
    const int wave = tid >> 6;
    const int wbase = wave * 32;          // col strip base for this wave
    const int c  = lane & 15;
    const int g  = lane >> 4;
    const int g4 = g * 4;

    const int b   = blockIdx.x / (NPTS / K2_PTS);
    const int m0  = (blockIdx.x % (NPTS / K2_PTS)) * K2_PTS;
    const size_t gp0 = (size_t)b * NPTS + m0;
    const size_t bN  = (size_t)b * NPTS;
    const float inv_sqrt_d = 0.08838834764831845f;

    // ---- P0: idx + rel ----
    if (tid < K2_R) {
        const int p = tid >> 4, j = tid & 15;
        const size_t m = gp0 + p;
        const int mi = m0 + p;
        IDX[tid] = grouped_idx[m * KNB + j];
#pragma unroll
        for (int cc = 0; cc < 3; ++cc)
            REL[tid * 3 + cc] = new_xyz[m * 3 + cc]
                              - grouped_xyz[(((size_t)b * 3 + cc) * NPTS + mi) * KNB + j];
    }
    __syncthreads();

    // ---- P1: inner1 = relu(rel @ dw1.T + db1) -> AB (bf16) ----
    for (int i = tid; i < K2_R * DM; i += 256) {
        const int r = i >> 7, f = i & (DM - 1);
        float v = db1[f];
        v = fmaf(REL[r * 3 + 0], dw1[f * 3 + 0], v);
        v = fmaf(REL[r * 3 + 1], dw1[f * 3 + 1], v);
        v = fmaf(REL[r * 3 + 2], dw1[f * 3 + 2], v);
        AB[r * ABSTR + f] = f2bf(fmaxf(v, 0.f));
    }
    __syncthreads();

    // ---- P2: GEMM1 pos = inner1 @ dw2.T + db2 -> POSL (f32) ----
    {
        f32x4 acc[4][2];
#pragma unroll
        for (int rt = 0; rt < 4; ++rt)
#pragma unroll
            for (int ct = 0; ct < 2; ++ct) acc[rt][ct] = (f32x4)0.f;
        mfma_gemm(AB, dw2, lane, wbase, acc);
#pragma unroll
        for (int ct = 0; ct < 2; ++ct) {
            const int col = wbase + ct * 16 + c;
            const float bb = db2[col];
#pragma unroll
            for (int rt = 0; rt < 4; ++rt)
#pragma unroll
                for (int rg = 0; rg < 4; ++rg)
                    POSL[(rt * 16 + g4 + rg) * PSTR + col] = acc[rt][ct][rg] + bb;
        }
    }
    __syncthreads();   // POSL ready; all GEMM1 reads of AB complete

    // ---- P3: h = q - k_gather + pos -> AB (bf16) ----
    for (int i = tid; i < K2_R * DM; i += 256) {
        const int r = i >> 7, f = i & (DM - 1);
        const int p = r >> 4;
        const float hv = qws[(gp0 + p) * DM + f]
                       - kws[(bN + IDX[r]) * DM + f]
                       + POSL[r * PSTR + f];
        AB[r * ABSTR + f] = f2bf(hv);
    }
    __syncthreads();

    // ---- P4: GEMM2 g1 = relu(h @ gw1.T + gb1) -> AB (bf16) ----
    {
        f32x4 acc[4][2];
#pragma unroll
        for (int rt = 0; rt < 4; ++rt)
#pragma unroll
            for (int ct = 0; ct < 2; ++ct) acc[rt][ct] = (f32x4)0.f;
        mfma_gemm(AB, gw1, lane, wbase, acc);
        __syncthreads();   // all reads of AB(h) done before overwrite
#pragma unroll
        for (int ct = 0; ct < 2; ++ct) {
            const int col = wbase + ct * 16 + c;
            const float bb = gb1[col];
#pragma unroll
            for (int rt = 0; rt < 4; ++rt)
#pragma unroll
                for (int rg = 0; rg < 4; ++rg)
                    AB[(rt * 16 + g4 + rg) * ABSTR + col] = f2bf(fmaxf(acc[rt][ct][rg] + bb, 0.f));
        }
    }
    __syncthreads();

    // ---- P5: GEMM3 logits = (g1 @ gw2.T + gb2) * inv_sqrt_d (stay in regs) ----
    f32x4 lg[4][2];
#pragma unroll
    for (int rt = 0; rt < 4; ++rt)
#pragma unroll
        for (int ct = 0; ct < 2; ++ct) lg[rt][ct] = (f32x4)0.f;
    mfma_gemm(AB, gw2, lane, wbase, lg);
#pragma unroll
    for (int ct = 0; ct < 2; ++ct) {
        const int col = wbase + ct * 16 + c;
        const float bb = gb2[col];
#pragma unroll
        for (int rt = 0; rt < 4; ++rt)
#pragma unroll
            for (int rg = 0; rg < 4; ++rg)
                lg[rt][ct][rg] = (lg[rt][ct][rg] + bb) * inv_sqrt_d;
    }

    // ---- P6/P7: in-register softmax over the 16 neighbors + output reduce ----
    // D layout: col = lane&15 (+ct*16+wbase), row (in tile) = g*4+rg; rowtile == point.
#pragma unroll
    for (int rt = 0; rt < 4; ++rt)
#pragma unroll
    for (int ct = 0; ct < 2; ++ct) {
        const int col = wbase + ct * 16 + c;
        f32x4 l = lg[rt][ct];
        float mx = fmaxf(fmaxf(l[0], l[1]), fmaxf(l[2], l[3]));
        mx = fmaxf(mx, __shfl_xor(mx, 16));
        mx = fmaxf(mx, __shfl_xor(mx, 32));
        f32x4 e;
        e[0] = __expf(l[0] - mx); e[1] = __expf(l[1] - mx);
        e[2] = __expf(l[2] - mx); e[3] = __expf(l[3] - mx);
        float s = e[0] + e[1] + e[2] + e[3];
        s += __shfl_xor(s, 16);
        s += __shfl_xor(s, 32);
        float o = 0.f;
#pragma unroll
        for (int rg = 0; rg < 4; ++rg) {
            const int row = rt * 16 + g4 + rg;
            const float vv = vws[(bN + IDX[row]) * DM + col] + POSL[row * PSTR + col];
            o = fmaf(e[rg], vv, o);
        }
        o += __shfl_xor(o, 16);
        o += __shfl_xor(o, 32);
        if (g == 0)
            out[(gp0 + rt) * DM + col] = o / s;
    }
}

// ======================= launch =======================
extern "C" void kernel_launch(void* const* d_in, const int* in_sizes, int n_in,
                              void* d_out, int out_size, void* d_ws, size_t ws_size,
                              hipStream_t stream)
{
    const float* new_xyz     = (const float*)d_in[0];
    const float* grouped_xyz = (const float*)d_in[1];
    const int*   grouped_idx = (const int*)d_in[2];
    const float* features    = (const float*)d_in[3];
    const float* fc1_w = (const float*)d_in[4];
    const float* fc1_b = (const float*)d_in[5];
    const float* wq    = (const float*)d_in[6];
    const float* wk    = (const float*)d_in[7];
    const float* wv    = (const float*)d_in[8];
    const float* dw1   = (const float*)d_in[9];
    const float* db1   = (const float*)d_in[10];
    const float* dw2   = (const float*)d_in[11];
    const float* db2   = (const float*)d_in[12];
    const float* gw1   = (const float*)d_in[13];
    const float* gb1   = (const float*)d_in[14];
    const float* gw2   = (const float*)d_in[15];
    const float* gb2   = (const float*)d_in[16];
    float* out = (float*)d_out;

    float* ws  = (float*)d_ws;
    const size_t npt = (size_t)BB * NPTS * DM;
    float* qws = ws;
    float* kws = ws + npt;
    float* vws = ws + 2 * npt;

    proj_kernel<<<(BB * NPTS) / K1_MT, 256, 0, stream>>>(
        features, fc1_w, fc1_b, wq, wk, wv, qws, kws, vws);

    attn_kernel<<<(BB * NPTS) / K2_PTS, 256, 0, stream>>>(
        new_xyz, grouped_xyz, grouped_idx,
        dw1, db1, dw2, db2, gw1, gb1, gw2, gb2,
        qws, kws, vws, out);
}

// Round 3
// 280.579 us; speedup vs baseline: 10.1224x; 1.3897x over previous
//
#include <hip/hip_runtime.h>
#include <math.h>

#define BB   2
#define NPTS 16384
#define KNB  16
#define DPTS 64
#define DM   128

typedef float  f32x4  __attribute__((ext_vector_type(4)));
typedef short  bf16x8 __attribute__((ext_vector_type(8)));

__device__ __forceinline__ unsigned short f2bf(float f) {
    union { float f; unsigned u; } v; v.f = f;
    unsigned r = v.u + 0x7FFFu + ((v.u >> 16) & 1u);   // RNE
    return (unsigned short)(r >> 16);
}
__device__ __forceinline__ float bf2f(unsigned short h) {
    union { unsigned u; float f; } v; v.u = ((unsigned)h) << 16;
    return v.f;
}

// ============ Kernel 0: one-shot weight conversion f32 -> bf16 ============
__global__ __launch_bounds__(256) void cvtw_kernel(
    const float* __restrict__ dw2, const float* __restrict__ gw1,
    const float* __restrict__ gw2, unsigned short* __restrict__ wb)
{
    const int i = blockIdx.x * 256 + threadIdx.x;   // 0 .. 3*16384-1
    const int which = i >> 14;                      // 16384 elems per matrix
    const int off   = i & 16383;
    const float* src = (which == 0) ? dw2 : (which == 1) ? gw1 : gw2;
    wb[i] = f2bf(src[off]);
}

// ============ Kernel 1: x = fc1(features); q/k/v (f32 math, bf16 out) =====
#define K1_MT 32

__global__ __launch_bounds__(256) void proj_kernel(
    const float* __restrict__ features,
    const float* __restrict__ fc1_w, const float* __restrict__ fc1_b,
    const float* __restrict__ wq, const float* __restrict__ wk, const float* __restrict__ wv,
    unsigned short* __restrict__ qws, unsigned short* __restrict__ kws,
    unsigned short* __restrict__ vws)
{
    __shared__ float featL[K1_MT][DPTS];
    __shared__ float xL[K1_MT][DM];
    const int tid = threadIdx.x;
    const size_t gp0 = (size_t)blockIdx.x * K1_MT;

    const float* fsrc = features + gp0 * DPTS;
    for (int i = tid; i < K1_MT * DPTS / 4; i += 256)
        ((float4*)featL)[i] = ((const float4*)fsrc)[i];
    __syncthreads();

    const int f  = tid & (DM - 1);
    const int r0 = (tid >> 7) * (K1_MT / 2);

    {
        float acc[K1_MT / 2];
        const float bia = fc1_b[f];
#pragma unroll
        for (int r = 0; r < K1_MT / 2; ++r) acc[r] = bia;
        for (int c = 0; c < DPTS; c += 4) {
            const float4 w4 = *(const float4*)&fc1_w[f * DPTS + c];
#pragma unroll
            for (int r = 0; r < K1_MT / 2; ++r) {
                const float4 a4 = *(const float4*)&featL[r0 + r][c];
                acc[r] = fmaf(a4.x, w4.x, fmaf(a4.y, w4.y, fmaf(a4.z, w4.z, fmaf(a4.w, w4.w, acc[r]))));
            }
        }
#pragma unroll
        for (int r = 0; r < K1_MT / 2; ++r) xL[r0 + r][f] = acc[r];
    }
    __syncthreads();

    float aq[K1_MT / 2], ak[K1_MT / 2], av[K1_MT / 2];
#pragma unroll
    for (int r = 0; r < K1_MT / 2; ++r) { aq[r] = 0.f; ak[r] = 0.f; av[r] = 0.f; }
    for (int c = 0; c < DM; c += 4) {
        const float4 wq4 = *(const float4*)&wq[f * DM + c];
        const float4 wk4 = *(const float4*)&wk[f * DM + c];
        const float4 wv4 = *(const float4*)&wv[f * DM + c];
#pragma unroll
        for (int r = 0; r < K1_MT / 2; ++r) {
            const float4 a4 = *(const float4*)&xL[r0 + r][c];
            aq[r] = fmaf(a4.x, wq4.x, fmaf(a4.y, wq4.y, fmaf(a4.z, wq4.z, fmaf(a4.w, wq4.w, aq[r]))));
            ak[r] = fmaf(a4.x, wk4.x, fmaf(a4.y, wk4.y, fmaf(a4.z, wk4.z, fmaf(a4.w, wk4.w, ak[r]))));
            av[r] = fmaf(a4.x, wv4.x, fmaf(a4.y, wv4.y, fmaf(a4.z, wv4.z, fmaf(a4.w, wv4.w, av[r]))));
        }
    }
#pragma unroll
    for (int r = 0; r < K1_MT / 2; ++r) {
        const size_t o = (gp0 + r0 + r) * DM + f;
        qws[o] = f2bf(aq[r]); kws[o] = f2bf(ak[r]); vws[o] = f2bf(av[r]);
    }
}

// ============ Kernel 2: fused neighbor pipeline (MFMA bf16) ===============
#define K2_PTS 4
#define K2_R   (K2_PTS * KNB)   // 64 rows
#define ABSTR  136              // bf16 elems per LDS row (272B, 16B-mult)

// GEMM over 64x128 act tile vs bf16 weights (32-col strip per wave)
__device__ __forceinline__ void mfma_gemm(const unsigned short* __restrict__ AB,
                                          const unsigned short* __restrict__ Wb,
                                          int lane, int wbase, f32x4 acc[4][2])
{
    const int c = lane & 15, g = lane >> 4;
    bf16x8 Bf[2][4];
#pragma unroll
    for (int ct = 0; ct < 2; ++ct)
#pragma unroll
        for (int ks = 0; ks < 4; ++ks)
            Bf[ct][ks] = *(const bf16x8*)&Wb[(wbase + ct * 16 + c) * DM + ks * 32 + g * 8];
#pragma unroll
    for (int rt = 0; rt < 4; ++rt) {
        bf16x8 Af[4];
#pragma unroll
        for (int ks = 0; ks < 4; ++ks)
            Af[ks] = *(const bf16x8*)&AB[(rt * 16 + c) * ABSTR + ks * 32 + g * 8];
#pragma unroll
        for (int ct = 0; ct < 2; ++ct)
#pragma unroll
            for (int ks = 0; ks < 4; ++ks)
                acc[rt][ct] = __builtin_amdgcn_mfma_f32_16x16x32_bf16(
                    Af[ks], Bf[ct][ks], acc[rt][ct], 0, 0, 0);
    }
}

__global__ __launch_bounds__(256, 4) void attn_kernel(
    const float* __restrict__ new_xyz, const float* __restrict__ grouped_xyz,
    const int* __restrict__ grouped_idx,
    const float* __restrict__ dw1, const float* __restrict__ db1,
    const float* __restrict__ db2,
    const float* __restrict__ gb1, const float* __restrict__ gb2,
    const unsigned short* __restrict__ wbf,     // [dw2 | gw1 | gw2] bf16
    const unsigned short* __restrict__ qws, const unsigned short* __restrict__ kws,
    const unsigned short* __restrict__ vws,
    float* __restrict__ out)
{
    __shared__ __align__(16) unsigned short AB[K2_R * ABSTR];    // 17408 B
    __shared__ __align__(16) unsigned short POSL[K2_R * ABSTR];  // 17408 B
    __shared__ float REL[K2_R * 3];
    __shared__ int   IDX[K2_R];

    const int tid  = threadIdx.x;
    const int lane = tid & 63;
    const int wave = tid >> 6;
    const int wbase = wave * 32;
    const int c  = lane & 15;
    const int g  = lane >> 4;
    const int g4 = g * 4;

    const int b   = blockIdx.x / (NPTS / K2_PTS);
    const int m0  = (blockIdx.x % (NPTS / K2_PTS)) * K2_PTS;
    const size_t gp0 = (size_t)b * NPTS + m0;
    const size_t bN  = (size_t)b * NPTS;
    const float inv_sqrt_d = 0.08838834764831845f;

    const unsigned short* dw2b = wbf;
    const unsigned short* gw1b = wbf + 16384;
    const unsigned short* gw2b = wbf + 32768;

    // ---- P0: idx + rel ----
    if (tid < K2_R) {
        const int p = tid >> 4, j = tid & 15;
        const size_t m = gp0 + p;
        const int mi = m0 + p;
        IDX[tid] = grouped_idx[m * KNB + j];
#pragma unroll
        for (int cc = 0; cc < 3; ++cc)
            REL[tid * 3 + cc] = new_xyz[m * 3 + cc]
                              - grouped_xyz[(((size_t)b * 3 + cc) * NPTS + mi) * KNB + j];
    }
    __syncthreads();

    // ---- P1: inner1 = relu(rel @ dw1.T + db1) -> AB (bf16) ----
    for (int i = tid; i < K2_R * DM; i += 256) {
        const int r = i >> 7, f = i & (DM - 1);
        float v = db1[f];
        v = fmaf(REL[r * 3 + 0], dw1[f * 3 + 0], v);
        v = fmaf(REL[r * 3 + 1], dw1[f * 3 + 1], v);
        v = fmaf(REL[r * 3 + 2], dw1[f * 3 + 2], v);
        AB[r * ABSTR + f] = f2bf(fmaxf(v, 0.f));
    }
    __syncthreads();

    // ---- P2: GEMM1 pos = inner1 @ dw2.T + db2 ; keep f32 in regs, bf16 -> POSL
    f32x4 posr[4][2];
    {
#pragma unroll
        for (int rt = 0; rt < 4; ++rt)
#pragma unroll
            for (int ct = 0; ct < 2; ++ct) posr[rt][ct] = (f32x4)0.f;
        mfma_gemm(AB, dw2b, lane, wbase, posr);
#pragma unroll
        for (int ct = 0; ct < 2; ++ct) {
            const int col = wbase + ct * 16 + c;
            const float bb = db2[col];
#pragma unroll
            for (int rt = 0; rt < 4; ++rt)
#pragma unroll
                for (int rg = 0; rg < 4; ++rg) {
                    posr[rt][ct][rg] += bb;
                    POSL[(rt * 16 + g4 + rg) * ABSTR + col] = f2bf(posr[rt][ct][rg]);
                }
        }
    }
    __syncthreads();   // POSL ready; GEMM1 reads of AB complete

    // ---- P3: h = q - k_gather + pos -> AB (bf16) ----
    for (int i = tid; i < K2_R * DM; i += 256) {
        const int r = i >> 7, f = i & (DM - 1);
        const int p = r >> 4;
        const float hv = bf2f(qws[(gp0 + p) * DM + f])
                       - bf2f(kws[(bN + IDX[r]) * DM + f])
                       + bf2f(POSL[r * ABSTR + f]);
        AB[r * ABSTR + f] = f2bf(hv);
    }
    __syncthreads();

    // ---- P4: GEMM2 g1 = relu(h @ gw1.T + gb1) -> AB (bf16) ----
    {
        f32x4 acc[4][2];
#pragma unroll
        for (int rt = 0; rt < 4; ++rt)
#pragma unroll
            for (int ct = 0; ct < 2; ++ct) acc[rt][ct] = (f32x4)0.f;
        mfma_gemm(AB, gw1b, lane, wbase, acc);
        __syncthreads();   // all reads of AB(h) done before overwrite
#pragma unroll
        for (int ct = 0; ct < 2; ++ct) {
            const int col = wbase + ct * 16 + c;
            const float bb = gb1[col];
#pragma unroll
            for (int rt = 0; rt < 4; ++rt)
#pragma unroll
                for (int rg = 0; rg < 4; ++rg)
                    AB[(rt * 16 + g4 + rg) * ABSTR + col] = f2bf(fmaxf(acc[rt][ct][rg] + bb, 0.f));
        }
    }
    __syncthreads();

    // ---- P5: GEMM3 logits = (g1 @ gw2.T + gb2) * inv_sqrt_d (stay in regs) --
    f32x4 lg[4][2];
#pragma unroll
    for (int rt = 0; rt < 4; ++rt)
#pragma unroll
        for (int ct = 0; ct < 2; ++ct) lg[rt][ct] = (f32x4)0.f;
    mfma_gemm(AB, gw2b, lane, wbase, lg);
#pragma unroll
    for (int ct = 0; ct < 2; ++ct) {
        const int col = wbase + ct * 16 + c;
        const float bb = gb2[col];
#pragma unroll
        for (int rt = 0; rt < 4; ++rt)
#pragma unroll
            for (int rg = 0; rg < 4; ++rg)
                lg[rt][ct][rg] = (lg[rt][ct][rg] + bb) * inv_sqrt_d;
    }

    // ---- P6: in-register softmax over 16 neighbors + output reduce ----
    // D layout: col = wbase+ct*16+(lane&15), row-in-tile = g*4+rg; rowtile == point.
#pragma unroll
    for (int rt = 0; rt < 4; ++rt)
#pragma unroll
    for (int ct = 0; ct < 2; ++ct) {
        const int col = wbase + ct * 16 + c;
        f32x4 l = lg[rt][ct];
        float mx = fmaxf(fmaxf(l[0], l[1]), fmaxf(l[2], l[3]));
        mx = fmaxf(mx, __shfl_xor(mx, 16));
        mx = fmaxf(mx, __shfl_xor(mx, 32));
        f32x4 e;
        e[0] = __expf(l[0] - mx); e[1] = __expf(l[1] - mx);
        e[2] = __expf(l[2] - mx); e[3] = __expf(l[3] - mx);
        float s = e[0] + e[1] + e[2] + e[3];
        s += __shfl_xor(s, 16);
        s += __shfl_xor(s, 32);
        float o = 0.f;
#pragma unroll
        for (int rg = 0; rg < 4; ++rg) {
            const int row = rt * 16 + g4 + rg;
            const float vv = bf2f(vws[(bN + IDX[row]) * DM + col]) + posr[rt][ct][rg];
            o = fmaf(e[rg], vv, o);
        }
        o += __shfl_xor(o, 16);
        o += __shfl_xor(o, 32);
        if (g == 0)
            out[(gp0 + rt) * DM + col] = o / s;
    }
}

// ======================= launch =======================
extern "C" void kernel_launch(void* const* d_in, const int* in_sizes, int n_in,
                              void* d_out, int out_size, void* d_ws, size_t ws_size,
                              hipStream_t stream)
{
    const float* new_xyz     = (const float*)d_in[0];
    const float* grouped_xyz = (const float*)d_in[1];
    const int*   grouped_idx = (const int*)d_in[2];
    const float* features    = (const float*)d_in[3];
    const float* fc1_w = (const float*)d_in[4];
    const float* fc1_b = (const float*)d_in[5];
    const float* wq    = (const float*)d_in[6];
    const float* wk    = (const float*)d_in[7];
    const float* wv    = (const float*)d_in[8];
    const float* dw1   = (const float*)d_in[9];
    const float* db1   = (const float*)d_in[10];
    const float* dw2   = (const float*)d_in[11];
    const float* db2   = (const float*)d_in[12];
    const float* gw1   = (const float*)d_in[13];
    const float* gb1   = (const float*)d_in[14];
    const float* gw2   = (const float*)d_in[15];
    const float* gb2   = (const float*)d_in[16];
    float* out = (float*)d_out;

    unsigned short* ws = (unsigned short*)d_ws;
    const size_t npt = (size_t)BB * NPTS * DM;   // 4,194,304 elems per array
    unsigned short* qws = ws;
    unsigned short* kws = ws + npt;
    unsigned short* vws = ws + 2 * npt;
    unsigned short* wbf = ws + 3 * npt;          // 3*16384 bf16 weights

    cvtw_kernel<<<(3 * DM * DM) / 256, 256, 0, stream>>>(dw2, gw1, gw2, wbf);

    proj_kernel<<<(BB * NPTS) / K1_MT, 256, 0, stream>>>(
        features, fc1_w, fc1_b, wq, wk, wv, qws, kws, vws);

    attn_kernel<<<(BB * NPTS) / K2_PTS, 256, 0, stream>>>(
        new_xyz, grouped_xyz, grouped_idx,
        dw1, db1, db2, gb1, gb2,
        wbf, qws, kws, vws, out);
}

// Round 4
// 175.272 us; speedup vs baseline: 16.2043x; 1.6008x over previous
//
#include <hip/hip_runtime.h>
#include <math.h>

#define BB   2
#define NPTS 16384
#define KNB  16
#define DPTS 64
#define DM   128

typedef float  f32x4  __attribute__((ext_vector_type(4)));
typedef short  bf16x8 __attribute__((ext_vector_type(8)));

__device__ __forceinline__ unsigned short f2bf(float f) {
    union { float f; unsigned u; } v; v.f = f;
    unsigned r = v.u + 0x7FFFu + ((v.u >> 16) & 1u);   // RNE
    return (unsigned short)(r >> 16);
}
__device__ __forceinline__ float bf2f(unsigned short h) {
    union { unsigned u; float f; } v; v.u = ((unsigned)h) << 16;
    return v.f;
}

// wbf layout (bf16 elems): [dw2 16K | gw1 16K | gw2 16K | wq 16K | wk 16K | wv 16K | fc1_w 8K]
#define WOFF_DW2  0
#define WOFF_GW1  16384
#define WOFF_GW2  32768
#define WOFF_WQ   49152
#define WOFF_WK   65536
#define WOFF_WV   81920
#define WOFF_FC1  98304
#define WTOT      106496

// ============ Kernel 0: one-shot weight conversion f32 -> bf16 ============
__global__ __launch_bounds__(256) void cvtw_kernel(
    const float* __restrict__ dw2, const float* __restrict__ gw1,
    const float* __restrict__ gw2, const float* __restrict__ wq,
    const float* __restrict__ wk, const float* __restrict__ wv,
    const float* __restrict__ fc1_w, unsigned short* __restrict__ wb)
{
    const int i = blockIdx.x * 256 + threadIdx.x;
    if (i >= WTOT) return;
    float v;
    if (i < WOFF_WQ) {
        const int which = i >> 14, off = i & 16383;
        v = (which == 0) ? dw2[off] : (which == 1) ? gw1[off] : gw2[off];
    } else if (i < WOFF_FC1) {
        const int j = i - WOFF_WQ;
        const int which = j >> 14, off = j & 16383;
        v = (which == 0) ? wq[off] : (which == 1) ? wk[off] : wv[off];
    } else {
        v = fc1_w[i - WOFF_FC1];
    }
    wb[i] = f2bf(v);
}

// shared GEMM helper: 64x128 act tile (stride 136) vs bf16 weights [128][128],
// 32-col strip per wave
#define ABSTR 136

__device__ __forceinline__ void mfma_gemm(const unsigned short* __restrict__ AB,
                                          const unsigned short* __restrict__ Wb,
                                          int lane, int wbase, f32x4 acc[4][2])
{
    const int c = lane & 15, g = lane >> 4;
    bf16x8 Bf[2][4];
#pragma unroll
    for (int ct = 0; ct < 2; ++ct)
#pragma unroll
        for (int ks = 0; ks < 4; ++ks)
            Bf[ct][ks] = *(const bf16x8*)&Wb[(wbase + ct * 16 + c) * DM + ks * 32 + g * 8];
#pragma unroll
    for (int rt = 0; rt < 4; ++rt) {
        bf16x8 Af[4];
#pragma unroll
        for (int ks = 0; ks < 4; ++ks)
            Af[ks] = *(const bf16x8*)&AB[(rt * 16 + c) * ABSTR + ks * 32 + g * 8];
#pragma unroll
        for (int ct = 0; ct < 2; ++ct)
#pragma unroll
            for (int ks = 0; ks < 4; ++ks)
                acc[rt][ct] = __builtin_amdgcn_mfma_f32_16x16x32_bf16(
                    Af[ks], Bf[ct][ks], acc[rt][ct], 0, 0, 0);
    }
}

// ============ Kernel 1: x = fc1(features); q/k/v  (MFMA bf16) =============
#define P_MT  64   // points per block
#define FSTR  72   // bf16 elems per FB row (144 B)

__global__ __launch_bounds__(256, 4) void proj_kernel(
    const float* __restrict__ features, const float* __restrict__ fc1_b,
    const unsigned short* __restrict__ wbf,
    unsigned short* __restrict__ qws, unsigned short* __restrict__ kws,
    unsigned short* __restrict__ vws)
{
    __shared__ __align__(16) unsigned short FB[P_MT * FSTR];   //  9216 B
    __shared__ __align__(16) unsigned short XB[P_MT * ABSTR];  // 17408 B

    const int tid  = threadIdx.x;
    const int lane = tid & 63;
    const int wave = tid >> 6;
    const int wbase = wave * 32;
    const int c  = lane & 15;
    const int g  = lane >> 4;
    const int g4 = g * 4;
    const size_t gp0 = (size_t)blockIdx.x * P_MT;

    // stage features (f32 -> bf16), 16B granularity
    for (int i = tid; i < P_MT * 8; i += 256) {
        const int r = i >> 3, o = i & 7;
        const float4 a = *(const float4*)&features[(gp0 + r) * DPTS + o * 8];
        const float4 b = *(const float4*)&features[(gp0 + r) * DPTS + o * 8 + 4];
        bf16x8 t;
        t[0] = (short)f2bf(a.x); t[1] = (short)f2bf(a.y);
        t[2] = (short)f2bf(a.z); t[3] = (short)f2bf(a.w);
        t[4] = (short)f2bf(b.x); t[5] = (short)f2bf(b.y);
        t[6] = (short)f2bf(b.z); t[7] = (short)f2bf(b.w);
        *(bf16x8*)&FB[r * FSTR + o * 8] = t;
    }
    __syncthreads();

    // GEMM0: x = features @ fc1_w.T + fc1_b  (K=64)
    {
        const unsigned short* fw = wbf + WOFF_FC1;
        f32x4 acc[4][2];
#pragma unroll
        for (int rt = 0; rt < 4; ++rt)
#pragma unroll
            for (int ct = 0; ct < 2; ++ct) acc[rt][ct] = (f32x4)0.f;
        bf16x8 Bf[2][2];
#pragma unroll
        for (int ct = 0; ct < 2; ++ct)
#pragma unroll
            for (int ks = 0; ks < 2; ++ks)
                Bf[ct][ks] = *(const bf16x8*)&fw[(wbase + ct * 16 + c) * DPTS + ks * 32 + g * 8];
#pragma unroll
        for (int rt = 0; rt < 4; ++rt) {
            bf16x8 Af[2];
#pragma unroll
            for (int ks = 0; ks < 2; ++ks)
                Af[ks] = *(const bf16x8*)&FB[(rt * 16 + c) * FSTR + ks * 32 + g * 8];
#pragma unroll
            for (int ct = 0; ct < 2; ++ct)
#pragma unroll
                for (int ks = 0; ks < 2; ++ks)
                    acc[rt][ct] = __builtin_amdgcn_mfma_f32_16x16x32_bf16(
                        Af[ks], Bf[ct][ks], acc[rt][ct], 0, 0, 0);
        }
#pragma unroll
        for (int ct = 0; ct < 2; ++ct) {
            const int col = wbase + ct * 16 + c;
            const float bb = fc1_b[col];
#pragma unroll
            for (int rt = 0; rt < 4; ++rt)
#pragma unroll
                for (int rg = 0; rg < 4; ++rg)
                    XB[(rt * 16 + g4 + rg) * ABSTR + col] = f2bf(acc[rt][ct][rg] + bb);
        }
    }
    __syncthreads();

    // GEMM q / k / v over XB (K=128), write bf16 to workspace
    const unsigned short* wmat[3] = { wbf + WOFF_WQ, wbf + WOFF_WK, wbf + WOFF_WV };
    unsigned short* outp[3] = { qws, kws, vws };
#pragma unroll
    for (int m = 0; m < 3; ++m) {
        f32x4 acc[4][2];
#pragma unroll
        for (int rt = 0; rt < 4; ++rt)
#pragma unroll
            for (int ct = 0; ct < 2; ++ct) acc[rt][ct] = (f32x4)0.f;
        mfma_gemm(XB, wmat[m], lane, wbase, acc);
#pragma unroll
        for (int ct = 0; ct < 2; ++ct) {
            const int col = wbase + ct * 16 + c;
#pragma unroll
            for (int rt = 0; rt < 4; ++rt)
#pragma unroll
                for (int rg = 0; rg < 4; ++rg)
                    outp[m][(gp0 + rt * 16 + g4 + rg) * DM + col] = f2bf(acc[rt][ct][rg]);
        }
    }
}

// ============ Kernel 2: fused neighbor pipeline (MFMA bf16) ===============
#define K2_PTS 4
#define K2_R   (K2_PTS * KNB)   // 64 rows

__global__ __launch_bounds__(256, 4) void attn_kernel(
    const float* __restrict__ new_xyz, const float* __restrict__ grouped_xyz,
    const int* __restrict__ grouped_idx,
    const float* __restrict__ dw1, const float* __restrict__ db1,
    const float* __restrict__ db2,
    const float* __restrict__ gb1, const float* __restrict__ gb2,
    const unsigned short* __restrict__ wbf,
    const unsigned short* __restrict__ qws, const unsigned short* __restrict__ kws,
    const unsigned short* __restrict__ vws,
    float* __restrict__ out)
{
    __shared__ __align__(16) unsigned short AB[K2_R * ABSTR];    // 17408 B
    __shared__ __align__(16) unsigned short POSL[K2_R * ABSTR];  // 17408 B
    __shared__ float REL[K2_R * 3];
    __shared__ int   IDX[K2_R];

    const int tid  = threadIdx.x;
    const int lane = tid & 63;
    const int wave = tid >> 6;
    const int wbase = wave * 32;
    const int c  = lane & 15;
    const int g  = lane >> 4;
    const int g4 = g * 4;
    const int rr = tid >> 4;        // row-within-group for vector phases
    const int o8 = (tid & 15) * 8;  // col octet base

    const int b   = blockIdx.x / (NPTS / K2_PTS);
    const int m0  = (blockIdx.x % (NPTS / K2_PTS)) * K2_PTS;
    const size_t gp0 = (size_t)b * NPTS + m0;
    const size_t bN  = (size_t)b * NPTS;
    const float inv_sqrt_d = 0.08838834764831845f;

    const unsigned short* dw2b = wbf + WOFF_DW2;
    const unsigned short* gw1b = wbf + WOFF_GW1;
    const unsigned short* gw2b = wbf + WOFF_GW2;

    // hoist dw1/db1 rows for this thread's col octet (fixed across iters)
    float wr[24], bbv[8];
    {
        const float4* wsrc = (const float4*)&dw1[o8 * 3];
#pragma unroll
        for (int t = 0; t < 6; ++t) ((float4*)wr)[t] = wsrc[t];
        const float4* bsrc = (const float4*)&db1[o8];
        ((float4*)bbv)[0] = bsrc[0];
        ((float4*)bbv)[1] = bsrc[1];
    }

    // ---- P0: idx + rel ----
    if (tid < K2_R) {
        const int p = tid >> 4, j = tid & 15;
        const size_t m = gp0 + p;
        const int mi = m0 + p;
        IDX[tid] = grouped_idx[m * KNB + j];
#pragma unroll
        for (int cc = 0; cc < 3; ++cc)
            REL[tid * 3 + cc] = new_xyz[m * 3 + cc]
                              - grouped_xyz[(((size_t)b * 3 + cc) * NPTS + mi) * KNB + j];
    }
    __syncthreads();

    // ---- P1: inner1 = relu(rel @ dw1.T + db1) -> AB (bf16, vectorized) ----
#pragma unroll
    for (int it = 0; it < 4; ++it) {
        const int r = it * 16 + rr;
        const float rx = REL[r * 3 + 0], ry = REL[r * 3 + 1], rz = REL[r * 3 + 2];
        bf16x8 t;
#pragma unroll
        for (int j = 0; j < 8; ++j) {
            float v = bbv[j];
            v = fmaf(rx, wr[j * 3 + 0], v);
            v = fmaf(ry, wr[j * 3 + 1], v);
            v = fmaf(rz, wr[j * 3 + 2], v);
            t[j] = (short)f2bf(fmaxf(v, 0.f));
        }
        *(bf16x8*)&AB[r * ABSTR + o8] = t;
    }
    __syncthreads();

    // ---- P2: GEMM1 pos = inner1 @ dw2.T + db2 ; f32 in regs, bf16 -> POSL --
    f32x4 posr[4][2];
    {
#pragma unroll
        for (int rt = 0; rt < 4; ++rt)
#pragma unroll
            for (int ct = 0; ct < 2; ++ct) posr[rt][ct] = (f32x4)0.f;
        mfma_gemm(AB, dw2b, lane, wbase, posr);
#pragma unroll
        for (int ct = 0; ct < 2; ++ct) {
            const int col = wbase + ct * 16 + c;
            const float bb = db2[col];
#pragma unroll
            for (int rt = 0; rt < 4; ++rt)
#pragma unroll
                for (int rg = 0; rg < 4; ++rg) {
                    posr[rt][ct][rg] += bb;
                    POSL[(rt * 16 + g4 + rg) * ABSTR + col] = f2bf(posr[rt][ct][rg]);
                }
        }
    }
    __syncthreads();

    // ---- P3: h = q - k_gather + pos -> AB (bf16, vectorized 16B) ----
#pragma unroll
    for (int it = 0; it < 4; ++it) {     // it == point p
        const int r = it * 16 + rr;
        const bf16x8 q8 = *(const bf16x8*)&qws[(gp0 + it) * DM + o8];
        const bf16x8 k8 = *(const bf16x8*)&kws[(bN + IDX[r]) * DM + o8];
        const bf16x8 p8 = *(const bf16x8*)&POSL[r * ABSTR + o8];
        bf16x8 t;
#pragma unroll
        for (int j = 0; j < 8; ++j) {
            const float hv = bf2f((unsigned short)q8[j])
                           - bf2f((unsigned short)k8[j])
                           + bf2f((unsigned short)p8[j]);
            t[j] = (short)f2bf(hv);
        }
        *(bf16x8*)&AB[r * ABSTR + o8] = t;
    }
    __syncthreads();

    // ---- P4: GEMM2 g1 = relu(h @ gw1.T + gb1) -> AB (bf16) ----
    {
        f32x4 acc[4][2];
#pragma unroll
        for (int rt = 0; rt < 4; ++rt)
#pragma unroll
            for (int ct = 0; ct < 2; ++ct) acc[rt][ct] = (f32x4)0.f;
        mfma_gemm(AB, gw1b, lane, wbase, acc);
        __syncthreads();   // all reads of AB(h) done before overwrite
#pragma unroll
        for (int ct = 0; ct < 2; ++ct) {
            const int col = wbase + ct * 16 + c;
            const float bb = gb1[col];
#pragma unroll
            for (int rt = 0; rt < 4; ++rt)
#pragma unroll
                for (int rg = 0; rg < 4; ++rg)
                    AB[(rt * 16 + g4 + rg) * ABSTR + col] = f2bf(fmaxf(acc[rt][ct][rg] + bb, 0.f));
        }
    }
    __syncthreads();

    // ---- P5: GEMM3 logits = (g1 @ gw2.T + gb2) * inv_sqrt_d (regs) ----
    f32x4 lg[4][2];
#pragma unroll
    for (int rt = 0; rt < 4; ++rt)
#pragma unroll
        for (int ct = 0; ct < 2; ++ct) lg[rt][ct] = (f32x4)0.f;
    mfma_gemm(AB, gw2b, lane, wbase, lg);
#pragma unroll
    for (int ct = 0; ct < 2; ++ct) {
        const int col = wbase + ct * 16 + c;
        const float bb = gb2[col];
#pragma unroll
        for (int rt = 0; rt < 4; ++rt)
#pragma unroll
            for (int rg = 0; rg < 4; ++rg)
                lg[rt][ct][rg] = (lg[rt][ct][rg] + bb) * inv_sqrt_d;
    }

    // ---- P6: in-register softmax over 16 neighbors + output reduce ----
#pragma unroll
    for (int rt = 0; rt < 4; ++rt)
#pragma unroll
    for (int ct = 0; ct < 2; ++ct) {
        const int col = wbase + ct * 16 + c;
        f32x4 l = lg[rt][ct];
        float mx = fmaxf(fmaxf(l[0], l[1]), fmaxf(l[2], l[3]));
        mx = fmaxf(mx, __shfl_xor(mx, 16));
        mx = fmaxf(mx, __shfl_xor(mx, 32));
        f32x4 e;
        e[0] = __expf(l[0] - mx); e[1] = __expf(l[1] - mx);
        e[2] = __expf(l[2] - mx); e[3] = __expf(l[3] - mx);
        float s = e[0] + e[1] + e[2] + e[3];
        s += __shfl_xor(s, 16);
        s += __shfl_xor(s, 32);
        float o = 0.f;
#pragma unroll
        for (int rg = 0; rg < 4; ++rg) {
            const int row = rt * 16 + g4 + rg;
            const float vv = bf2f(vws[(bN + IDX[row]) * DM + col]) + posr[rt][ct][rg];
            o = fmaf(e[rg], vv, o);
        }
        o += __shfl_xor(o, 16);
        o += __shfl_xor(o, 32);
        if (g == 0)
            out[(gp0 + rt) * DM + col] = o / s;
    }
}

// ======================= launch =======================
extern "C" void kernel_launch(void* const* d_in, const int* in_sizes, int n_in,
                              void* d_out, int out_size, void* d_ws, size_t ws_size,
                              hipStream_t stream)
{
    const float* new_xyz     = (const float*)d_in[0];
    const float* grouped_xyz = (const float*)d_in[1];
    const int*   grouped_idx = (const int*)d_in[2];
    const float* features    = (const float*)d_in[3];
    const float* fc1_w = (const float*)d_in[4];
    const float* fc1_b = (const float*)d_in[5];
    const float* wq    = (const float*)d_in[6];
    const float* wk    = (const float*)d_in[7];
    const float* wv    = (const float*)d_in[8];
    const float* dw1   = (const float*)d_in[9];
    const float* db1   = (const float*)d_in[10];
    const float* dw2   = (const float*)d_in[11];
    const float* db2   = (const float*)d_in[12];
    const float* gw1   = (const float*)d_in[13];
    const float* gb1   = (const float*)d_in[14];
    const float* gw2   = (const float*)d_in[15];
    const float* gb2   = (const float*)d_in[16];
    float* out = (float*)d_out;

    unsigned short* ws = (unsigned short*)d_ws;
    const size_t npt = (size_t)BB * NPTS * DM;
    unsigned short* qws = ws;
    unsigned short* kws = ws + npt;
    unsigned short* vws = ws + 2 * npt;
    unsigned short* wbf = ws + 3 * npt;

    cvtw_kernel<<<(WTOT + 255) / 256, 256, 0, stream>>>(
        dw2, gw1, gw2, wq, wk, wv, fc1_w, wbf);

    proj_kernel<<<(BB * NPTS) / P_MT, 256, 0, stream>>>(
        features, fc1_b, wbf, qws, kws, vws);

    attn_kernel<<<(BB * NPTS) / K2_PTS, 256, 0, stream>>>(
        new_xyz, grouped_xyz, grouped_idx,
        dw1, db1, db2, gb1, gb2,
        wbf, qws, kws, vws, out);
}

// Round 5
// 166.950 us; speedup vs baseline: 17.0120x; 1.0498x over previous
//
#include <hip/hip_runtime.h>
#include <hip/hip_bf16.h>
#include <math.h>

#define BB   2
#define NPTS 16384
#define KNB  16
#define DPTS 64
#define DM   128

typedef float  f32x4  __attribute__((ext_vector_type(4)));
typedef short  bf16x8 __attribute__((ext_vector_type(8)));

// f32 -> bf16 RNE via compiler cast (emits v_cvt_pk_bf16_f32 on gfx950; m240)
__device__ __forceinline__ unsigned short f2bf(float f) {
    union { __hip_bfloat16 h; unsigned short u; } v;
    v.h = __float2bfloat16(f);
    return v.u;
}
__device__ __forceinline__ float bf2f(unsigned short h) {
    union { unsigned u; float f; } v; v.u = ((unsigned)h) << 16;
    return v.f;
}

// wbf layout (bf16 elems): [dw2 16K | gw1 16K | gw2 16K | wq 16K | wk 16K | wv 16K | fc1_w 8K]
#define WOFF_DW2  0
#define WOFF_GW1  16384
#define WOFF_GW2  32768
#define WOFF_WQ   49152
#define WOFF_WK   65536
#define WOFF_WV   81920
#define WOFF_FC1  98304
#define WTOT      106496

// ============ Kernel 0: one-shot weight conversion f32 -> bf16 ============
__global__ __launch_bounds__(256) void cvtw_kernel(
    const float* __restrict__ dw2, const float* __restrict__ gw1,
    const float* __restrict__ gw2, const float* __restrict__ wq,
    const float* __restrict__ wk, const float* __restrict__ wv,
    const float* __restrict__ fc1_w, unsigned short* __restrict__ wb)
{
    const int i = blockIdx.x * 256 + threadIdx.x;
    if (i >= WTOT) return;
    float v;
    if (i < WOFF_WQ) {
        const int which = i >> 14, off = i & 16383;
        v = (which == 0) ? dw2[off] : (which == 1) ? gw1[off] : gw2[off];
    } else if (i < WOFF_FC1) {
        const int j = i - WOFF_WQ;
        const int which = j >> 14, off = j & 16383;
        v = (which == 0) ? wq[off] : (which == 1) ? wk[off] : wv[off];
    } else {
        v = fc1_w[i - WOFF_FC1];
    }
    wb[i] = f2bf(v);
}

// shared GEMM helper: 64x128 act tile (stride 136) vs bf16 weights [128][128],
// 32-col strip per wave
#define ABSTR 136

__device__ __forceinline__ void mfma_gemm(const unsigned short* __restrict__ AB,
                                          const unsigned short* __restrict__ Wb,
                                          int lane, int wbase, f32x4 acc[4][2])
{
    const int c = lane & 15, g = lane >> 4;
    bf16x8 Bf[2][4];
#pragma unroll
    for (int ct = 0; ct < 2; ++ct)
#pragma unroll
        for (int ks = 0; ks < 4; ++ks)
            Bf[ct][ks] = *(const bf16x8*)&Wb[(wbase + ct * 16 + c) * DM + ks * 32 + g * 8];
#pragma unroll
    for (int rt = 0; rt < 4; ++rt) {
        bf16x8 Af[4];
#pragma unroll
        for (int ks = 0; ks < 4; ++ks)
            Af[ks] = *(const bf16x8*)&AB[(rt * 16 + c) * ABSTR + ks * 32 + g * 8];
#pragma unroll
        for (int ct = 0; ct < 2; ++ct)
#pragma unroll
            for (int ks = 0; ks < 4; ++ks)
                acc[rt][ct] = __builtin_amdgcn_mfma_f32_16x16x32_bf16(
                    Af[ks], Bf[ct][ks], acc[rt][ct], 0, 0, 0);
    }
}

// ============ Kernel 1: x = fc1(features); q/k/v  (MFMA bf16) =============
#define P_MT  64   // points per block
#define FSTR  72   // bf16 elems per FB row (144 B)

__global__ __launch_bounds__(256, 4) void proj_kernel(
    const float* __restrict__ features, const float* __restrict__ fc1_b,
    const unsigned short* __restrict__ wbf,
    unsigned short* __restrict__ qws, unsigned short* __restrict__ kws,
    unsigned short* __restrict__ vws)
{
    __shared__ __align__(16) unsigned short FB[P_MT * FSTR];   //  9216 B
    __shared__ __align__(16) unsigned short XB[P_MT * ABSTR];  // 17408 B

    const int tid  = threadIdx.x;
    const int lane = tid & 63;
    const int wave = tid >> 6;
    const int wbase = wave * 32;
    const int c  = lane & 15;
    const int g  = lane >> 4;
    const int g4 = g * 4;
    const size_t gp0 = (size_t)blockIdx.x * P_MT;

    // stage features (f32 -> bf16), 16B granularity
    for (int i = tid; i < P_MT * 8; i += 256) {
        const int r = i >> 3, o = i & 7;
        const float4 a = *(const float4*)&features[(gp0 + r) * DPTS + o * 8];
        const float4 b = *(const float4*)&features[(gp0 + r) * DPTS + o * 8 + 4];
        bf16x8 t;
        t[0] = (short)f2bf(a.x); t[1] = (short)f2bf(a.y);
        t[2] = (short)f2bf(a.z); t[3] = (short)f2bf(a.w);
        t[4] = (short)f2bf(b.x); t[5] = (short)f2bf(b.y);
        t[6] = (short)f2bf(b.z); t[7] = (short)f2bf(b.w);
        *(bf16x8*)&FB[r * FSTR + o * 8] = t;
    }
    __syncthreads();

    // GEMM0: x = features @ fc1_w.T + fc1_b  (K=64)
    {
        const unsigned short* fw = wbf + WOFF_FC1;
        f32x4 acc[4][2];
#pragma unroll
        for (int rt = 0; rt < 4; ++rt)
#pragma unroll
            for (int ct = 0; ct < 2; ++ct) acc[rt][ct] = (f32x4)0.f;
        bf16x8 Bf[2][2];
#pragma unroll
        for (int ct = 0; ct < 2; ++ct)
#pragma unroll
            for (int ks = 0; ks < 2; ++ks)
                Bf[ct][ks] = *(const bf16x8*)&fw[(wbase + ct * 16 + c) * DPTS + ks * 32 + g * 8];
#pragma unroll
        for (int rt = 0; rt < 4; ++rt) {
            bf16x8 Af[2];
#pragma unroll
            for (int ks = 0; ks < 2; ++ks)
                Af[ks] = *(const bf16x8*)&FB[(rt * 16 + c) * FSTR + ks * 32 + g * 8];
#pragma unroll
            for (int ct = 0; ct < 2; ++ct)
#pragma unroll
                for (int ks = 0; ks < 2; ++ks)
                    acc[rt][ct] = __builtin_amdgcn_mfma_f32_16x16x32_bf16(
                        Af[ks], Bf[ct][ks], acc[rt][ct], 0, 0, 0);
        }
#pragma unroll
        for (int ct = 0; ct < 2; ++ct) {
            const int col = wbase + ct * 16 + c;
            const float bb = fc1_b[col];
#pragma unroll
            for (int rt = 0; rt < 4; ++rt)
#pragma unroll
                for (int rg = 0; rg < 4; ++rg)
                    XB[(rt * 16 + g4 + rg) * ABSTR + col] = f2bf(acc[rt][ct][rg] + bb);
        }
    }
    __syncthreads();

    // GEMM q / k / v over XB (K=128), write bf16 to workspace
    const unsigned short* wmat[3] = { wbf + WOFF_WQ, wbf + WOFF_WK, wbf + WOFF_WV };
    unsigned short* outp[3] = { qws, kws, vws };
#pragma unroll
    for (int m = 0; m < 3; ++m) {
        f32x4 acc[4][2];
#pragma unroll
        for (int rt = 0; rt < 4; ++rt)
#pragma unroll
            for (int ct = 0; ct < 2; ++ct) acc[rt][ct] = (f32x4)0.f;
        mfma_gemm(XB, wmat[m], lane, wbase, acc);
#pragma unroll
        for (int ct = 0; ct < 2; ++ct) {
            const int col = wbase + ct * 16 + c;
#pragma unroll
            for (int rt = 0; rt < 4; ++rt)
#pragma unroll
                for (int rg = 0; rg < 4; ++rg)
                    outp[m][(gp0 + rt * 16 + g4 + rg) * DM + col] = f2bf(acc[rt][ct][rg]);
        }
    }
}

// ============ Kernel 2: fused neighbor pipeline (MFMA bf16) ===============
#define K2_PTS 4
#define K2_R   (K2_PTS * KNB)   // 64 rows

__global__ __launch_bounds__(256, 4) void attn_kernel(
    const float* __restrict__ new_xyz, const float* __restrict__ grouped_xyz,
    const int* __restrict__ grouped_idx,
    const float* __restrict__ dw1, const float* __restrict__ db1,
    const float* __restrict__ db2,
    const float* __restrict__ gb1, const float* __restrict__ gb2,
    const unsigned short* __restrict__ wbf,
    const unsigned short* __restrict__ qws, const unsigned short* __restrict__ kws,
    const unsigned short* __restrict__ vws,
    float* __restrict__ out)
{
    __shared__ __align__(16) unsigned short AB[K2_R * ABSTR];  // 17408 B
    __shared__ __align__(16) unsigned short SB[K2_R * ABSTR];  // 17408 B (pos, then g1)
    __shared__ float REL[K2_R * 3];
    __shared__ int   IDX[K2_R];

    const int tid  = threadIdx.x;
    const int lane = tid & 63;
    const int wave = tid >> 6;
    const int wbase = wave * 32;
    const int c  = lane & 15;
    const int g  = lane >> 4;
    const int g4 = g * 4;
    const int rr = tid >> 4;        // row-within-group for vector phases
    const int o8 = (tid & 15) * 8;  // col octet base

    const int b   = blockIdx.x / (NPTS / K2_PTS);
    const int m0  = (blockIdx.x % (NPTS / K2_PTS)) * K2_PTS;
    const size_t gp0 = (size_t)b * NPTS + m0;
    const size_t bN  = (size_t)b * NPTS;
    // 1/sqrt(128) * log2(e): use exp2 for softmax
    const float SCL = 0.12751743342f;

    const unsigned short* dw2b = wbf + WOFF_DW2;
    const unsigned short* gw1b = wbf + WOFF_GW1;
    const unsigned short* gw2b = wbf + WOFF_GW2;

    // hoist dw1/db1 rows for this thread's col octet (fixed across iters)
    float wr[24], bbv[8];
    {
        const float4* wsrc = (const float4*)&dw1[o8 * 3];
#pragma unroll
        for (int t = 0; t < 6; ++t) ((float4*)wr)[t] = wsrc[t];
        const float4* bsrc = (const float4*)&db1[o8];
        ((float4*)bbv)[0] = bsrc[0];
        ((float4*)bbv)[1] = bsrc[1];
    }

    // ---- P0: idx + rel ----
    if (tid < K2_R) {
        const int p = tid >> 4, j = tid & 15;
        const size_t m = gp0 + p;
        const int mi = m0 + p;
        IDX[tid] = grouped_idx[m * KNB + j];
#pragma unroll
        for (int cc = 0; cc < 3; ++cc)
            REL[tid * 3 + cc] = new_xyz[m * 3 + cc]
                              - grouped_xyz[(((size_t)b * 3 + cc) * NPTS + mi) * KNB + j];
    }
    __syncthreads();

    // ---- prefetch q/k gathers (T14: issue-early, consume in P3) ----
    bf16x8 q8[4], k8[4];
#pragma unroll
    for (int it = 0; it < 4; ++it) {
        const int r = it * 16 + rr;
        q8[it] = *(const bf16x8*)&qws[(gp0 + it) * DM + o8];
        k8[it] = *(const bf16x8*)&kws[(bN + IDX[r]) * DM + o8];
    }

    // ---- P1: inner1 = relu(rel @ dw1.T + db1) -> AB (bf16, vectorized) ----
#pragma unroll
    for (int it = 0; it < 4; ++it) {
        const int r = it * 16 + rr;
        const float rx = REL[r * 3 + 0], ry = REL[r * 3 + 1], rz = REL[r * 3 + 2];
        bf16x8 t;
#pragma unroll
        for (int j = 0; j < 8; ++j) {
            float v = bbv[j];
            v = fmaf(rx, wr[j * 3 + 0], v);
            v = fmaf(ry, wr[j * 3 + 1], v);
            v = fmaf(rz, wr[j * 3 + 2], v);
            t[j] = (short)f2bf(fmaxf(v, 0.f));
        }
        *(bf16x8*)&AB[r * ABSTR + o8] = t;
    }
    __syncthreads();

    // ---- P2: GEMM1 pos = inner1 @ dw2.T + db2 ; f32 in regs, bf16 -> SB ----
    f32x4 posr[4][2];
    {
#pragma unroll
        for (int rt = 0; rt < 4; ++rt)
#pragma unroll
            for (int ct = 0; ct < 2; ++ct) posr[rt][ct] = (f32x4)0.f;
        mfma_gemm(AB, dw2b, lane, wbase, posr);
#pragma unroll
        for (int ct = 0; ct < 2; ++ct) {
            const int col = wbase + ct * 16 + c;
            const float bb = db2[col];
#pragma unroll
            for (int rt = 0; rt < 4; ++rt)
#pragma unroll
                for (int rg = 0; rg < 4; ++rg) {
                    posr[rt][ct][rg] += bb;
                    SB[(rt * 16 + g4 + rg) * ABSTR + col] = f2bf(posr[rt][ct][rg]);
                }
        }
    }
    __syncthreads();

    // ---- P3: h = q - k_gather + pos -> AB (bf16, prefetched q/k) ----
#pragma unroll
    for (int it = 0; it < 4; ++it) {
        const int r = it * 16 + rr;
        const bf16x8 p8 = *(const bf16x8*)&SB[r * ABSTR + o8];
        bf16x8 t;
#pragma unroll
        for (int j = 0; j < 8; ++j) {
            const float hv = bf2f((unsigned short)q8[it][j])
                           - bf2f((unsigned short)k8[it][j])
                           + bf2f((unsigned short)p8[j]);
            t[j] = (short)f2bf(hv);
        }
        *(bf16x8*)&AB[r * ABSTR + o8] = t;
    }
    __syncthreads();

    // ---- P4: GEMM2 g1 = relu(h @ gw1.T + gb1) -> SB (pos dead; no mid-barrier)
    {
        f32x4 acc[4][2];
#pragma unroll
        for (int rt = 0; rt < 4; ++rt)
#pragma unroll
            for (int ct = 0; ct < 2; ++ct) acc[rt][ct] = (f32x4)0.f;
        mfma_gemm(AB, gw1b, lane, wbase, acc);
#pragma unroll
        for (int ct = 0; ct < 2; ++ct) {
            const int col = wbase + ct * 16 + c;
            const float bb = gb1[col];
#pragma unroll
            for (int rt = 0; rt < 4; ++rt)
#pragma unroll
                for (int rg = 0; rg < 4; ++rg)
                    SB[(rt * 16 + g4 + rg) * ABSTR + col] = f2bf(fmaxf(acc[rt][ct][rg] + bb, 0.f));
        }
    }
    __syncthreads();

    // ---- P5: GEMM3 logits = (g1 @ gw2.T + gb2) * scl (regs) ----
    f32x4 lg[4][2];
#pragma unroll
    for (int rt = 0; rt < 4; ++rt)
#pragma unroll
        for (int ct = 0; ct < 2; ++ct) lg[rt][ct] = (f32x4)0.f;
    mfma_gemm(SB, gw2b, lane, wbase, lg);
#pragma unroll
    for (int ct = 0; ct < 2; ++ct) {
        const int col = wbase + ct * 16 + c;
        const float bb = gb2[col];
#pragma unroll
        for (int rt = 0; rt < 4; ++rt)
#pragma unroll
            for (int rg = 0; rg < 4; ++rg)
                lg[rt][ct][rg] = (lg[rt][ct][rg] + bb) * SCL;
    }

    // ---- P6: in-register softmax over 16 neighbors + output reduce ----
    // D layout: col = wbase+ct*16+c, row-in-tile = g*4+rg; rowtile == point.
#pragma unroll
    for (int rt = 0; rt < 4; ++rt)
#pragma unroll
    for (int ct = 0; ct < 2; ++ct) {
        const int col = wbase + ct * 16 + c;
        f32x4 l = lg[rt][ct];
        float mx = fmaxf(fmaxf(l[0], l[1]), fmaxf(l[2], l[3]));
        mx = fmaxf(mx, __shfl_xor(mx, 16));
        mx = fmaxf(mx, __shfl_xor(mx, 32));
        f32x4 e;
        e[0] = __builtin_amdgcn_exp2f(l[0] - mx);
        e[1] = __builtin_amdgcn_exp2f(l[1] - mx);
        e[2] = __builtin_amdgcn_exp2f(l[2] - mx);
        e[3] = __builtin_amdgcn_exp2f(l[3] - mx);
        float s = e[0] + e[1] + e[2] + e[3];
        s += __shfl_xor(s, 16);
        s += __shfl_xor(s, 32);
        float o = 0.f;
#pragma unroll
        for (int rg = 0; rg < 4; ++rg) {
            const int row = rt * 16 + g4 + rg;
            const float vv = bf2f(vws[(bN + IDX[row]) * DM + col]) + posr[rt][ct][rg];
            o = fmaf(e[rg], vv, o);
        }
        o += __shfl_xor(o, 16);
        o += __shfl_xor(o, 32);
        if (g == 0)
            out[(gp0 + rt) * DM + col] = o * __builtin_amdgcn_rcpf(s);
    }
}

// ======================= launch =======================
extern "C" void kernel_launch(void* const* d_in, const int* in_sizes, int n_in,
                              void* d_out, int out_size, void* d_ws, size_t ws_size,
                              hipStream_t stream)
{
    const float* new_xyz     = (const float*)d_in[0];
    const float* grouped_xyz = (const float*)d_in[1];
    const int*   grouped_idx = (const int*)d_in[2];
    const float* features    = (const float*)d_in[3];
    const float* fc1_w = (const float*)d_in[4];
    const float* fc1_b = (const float*)d_in[5];
    const float* wq    = (const float*)d_in[6];
    const float* wk    = (const float*)d_in[7];
    const float* wv    = (const float*)d_in[8];
    const float* dw1   = (const float*)d_in[9];
    const float* db1   = (const float*)d_in[10];
    const float* dw2   = (const float*)d_in[11];
    const float* db2   = (const float*)d_in[12];
    const float* gw1   = (const float*)d_in[13];
    const float* gb1   = (const float*)d_in[14];
    const float* gw2   = (const float*)d_in[15];
    const float* gb2   = (const float*)d_in[16];
    float* out = (float*)d_out;

    unsigned short* ws = (unsigned short*)d_ws;
    const size_t npt = (size_t)BB * NPTS * DM;
    unsigned short* qws = ws;
    unsigned short* kws = ws + npt;
    unsigned short* vws = ws + 2 * npt;
    unsigned short* wbf = ws + 3 * npt;

    cvtw_kernel<<<(WTOT + 255) / 256, 256, 0, stream>>>(
        dw2, gw1, gw2, wq, wk, wv, fc1_w, wbf);

    proj_kernel<<<(BB * NPTS) / P_MT, 256, 0, stream>>>(
        features, fc1_b, wbf, qws, kws, vws);

    attn_kernel<<<(BB * NPTS) / K2_PTS, 256, 0, stream>>>(
        new_xyz, grouped_xyz, grouped_idx,
        dw1, db1, db2, gb1, gb2,
        wbf, qws, kws, vws, out);
}